// Round 9
// baseline (195.142 us; speedup 1.0000x reference)
//
#include <hip/hip_runtime.h>

#define NUM_CLASSES 19

typedef int v4i __attribute__((ext_vector_type(4)));

// Round-7 body (best: 186.6us — NT slab loads) with the reduce DISPATCH
// eliminated: each block atomicAdds its scaled partial into out. 1024
// atomics spread over the kernel's runtime (~4 block generations/CU) ->
// negligible serialization (unlike r1's 32768 back-to-back, 425us; and
// unlike r6's fence+counter+tail-reduce fusion, which regressed).
__global__ __launch_bounds__(256) void seg_loss_partial(
    const float* __restrict__ preds,
    const int*   __restrict__ targets,
    float*       __restrict__ out,
    float inv_total)
{
    const int tid = threadIdx.x;
    // one block per 32x1024 slab (128 KB contiguous); base = bid*32768
    const int* base = targets + (blockIdx.x << 15);

    unsigned mask = 0u;
    #pragma unroll 4
    for (int r = 0; r < 32; ++r) {
        const v4i v = __builtin_nontemporal_load(
            (const v4i*)(base + (r << 10) + (tid << 2)));
        mask |= (1u << v.x) | (1u << v.y) | (1u << v.z) | (1u << v.w);
    }

    // fold the 8 consecutive threads sharing a tile (within one wave)
    mask |= __shfl_xor(mask, 1);
    mask |= __shfl_xor(mask, 2);
    mask |= __shfl_xor(mask, 4);

    __shared__ unsigned tile_mask[32];
    if ((tid & 7) == 0) tile_mask[tid >> 3] = mask;
    __syncthreads();

    // BCE terms: tile = tid>>3 (32 tiles x 8 threads), classes c, c+8, c+16
    const int tile = tid >> 3;
    const int n    = (blockIdx.x << 5) + tile;      // global tile id
    const unsigned m = tile_mask[tile];
    float loss = 0.0f;
    #pragma unroll
    for (int j = 0; j < 3; ++j) {
        const int c = (tid & 7) + (j << 3);
        if (c < NUM_CLASSES) {
            const float x  = preds[n * NUM_CLASSES + c];
            const float tv = ((m >> c) & 1u) ? 1.0f : 0.0f;
            // stable BCE term: softplus(x) - t*x
            const float sp = fmaxf(x, 0.0f) + log1pf(__expf(-fabsf(x)));
            loss += sp - tv * x;
        }
    }

    // block reduction
    loss += __shfl_xor(loss, 1);
    loss += __shfl_xor(loss, 2);
    loss += __shfl_xor(loss, 4);
    loss += __shfl_xor(loss, 8);
    loss += __shfl_xor(loss, 16);
    loss += __shfl_xor(loss, 32);

    __shared__ float wsum[4];
    if ((tid & 63) == 0) wsum[tid >> 6] = loss;
    __syncthreads();
    if (tid == 0)
        atomicAdd(out, (wsum[0] + wsum[1] + wsum[2] + wsum[3]) * inv_total);
}

extern "C" void kernel_launch(void* const* d_in, const int* in_sizes, int n_in,
                              void* d_out, int out_size, void* d_ws, size_t ws_size,
                              hipStream_t stream) {
    const float* preds   = (const float*)d_in[0];
    const int*   targets = (const int*)d_in[1];
    float*       out     = (float*)d_out;

    const int n_tiles  = in_sizes[0] / NUM_CLASSES;   // 32768
    const int n_blocks = n_tiles / 32;                // 1024 slabs
    const float inv_total = 1.0f / (float)(n_tiles * NUM_CLASSES);

    // out is poisoned 0xAA before every timed call — zero it (4 B).
    hipMemsetAsync(out, 0, sizeof(float), stream);

    seg_loss_partial<<<n_blocks, 256, 0, stream>>>(preds, targets, out, inv_total);
}

// Round 10
// 187.183 us; speedup vs baseline: 1.0425x; 1.0425x over previous
//
#include <hip/hip_runtime.h>

#define NUM_CLASSES 19

typedef int v4i __attribute__((ext_vector_type(4)));

// Round-7 structure (NT slab loads, two kernels — best: 186.6us) with
// 512 threads/block: 8 waves/block x 4 blocks/CU = 32 waves/CU (vs 16),
// doubling CU-level NT-load concurrency. Each iteration the block loads
// 2 full 4KB rows (8KB contiguous). Thread t = (half=t>>8, col=t&255);
// half 0 covers rows 0..15, half 1 rows 16..31. Per-tile mask: 3 shuffle
// folds within each half, then LDS atomicOr combines the two halves.
__global__ __launch_bounds__(512) void seg_loss_partial(
    const float* __restrict__ preds,
    const int*   __restrict__ targets,
    float*       __restrict__ partial)
{
    const int tid  = threadIdx.x;
    const int col  = tid & 255;
    const int half = tid >> 8;
    // one block per 32x1024 slab (128 KB contiguous); base = bid*32768
    const int* base = targets + (blockIdx.x << 15) + (half << 14) + (col << 2);

    unsigned mask = 0u;
    #pragma unroll 4
    for (int r = 0; r < 16; ++r) {
        const v4i v = __builtin_nontemporal_load((const v4i*)(base + (r << 10)));
        mask |= (1u << v.x) | (1u << v.y) | (1u << v.z) | (1u << v.w);
    }

    // fold the 8 consecutive threads sharing a tile (same half, same wave)
    mask |= __shfl_xor(mask, 1);
    mask |= __shfl_xor(mask, 2);
    mask |= __shfl_xor(mask, 4);

    __shared__ unsigned tile_mask[32];
    if (tid < 32) tile_mask[tid] = 0u;
    __syncthreads();
    if ((tid & 7) == 0) atomicOr(&tile_mask[col >> 3], mask);
    __syncthreads();

    // BCE terms: half 0 only — tile = col>>3, classes c, c+8, c+16
    float loss = 0.0f;
    if (half == 0) {
        const int tile = col >> 3;
        const int n    = (blockIdx.x << 5) + tile;      // global tile id
        const unsigned m = tile_mask[tile];
        #pragma unroll
        for (int j = 0; j < 3; ++j) {
            const int c = (col & 7) + (j << 3);
            if (c < NUM_CLASSES) {
                const float x  = preds[n * NUM_CLASSES + c];
                const float tv = ((m >> c) & 1u) ? 1.0f : 0.0f;
                // stable BCE term: softplus(x) - t*x
                const float sp = fmaxf(x, 0.0f) + log1pf(__expf(-fabsf(x)));
                loss += sp - tv * x;
            }
        }
    }

    // block reduction (8 waves)
    loss += __shfl_xor(loss, 1);
    loss += __shfl_xor(loss, 2);
    loss += __shfl_xor(loss, 4);
    loss += __shfl_xor(loss, 8);
    loss += __shfl_xor(loss, 16);
    loss += __shfl_xor(loss, 32);

    __shared__ float wsum[8];
    if ((tid & 63) == 0) wsum[tid >> 6] = loss;
    __syncthreads();
    if (tid == 0) {
        float s = 0.0f;
        #pragma unroll
        for (int w = 0; w < 8; ++w) s += wsum[w];
        partial[blockIdx.x] = s;
    }
}

__global__ __launch_bounds__(256) void seg_loss_reduce(
    const float* __restrict__ partial,
    float*       __restrict__ out,
    float inv_total, int nblocks)
{
    float s = 0.0f;
    for (int i = threadIdx.x; i < nblocks; i += 256) s += partial[i];

    s += __shfl_xor(s, 1);
    s += __shfl_xor(s, 2);
    s += __shfl_xor(s, 4);
    s += __shfl_xor(s, 8);
    s += __shfl_xor(s, 16);
    s += __shfl_xor(s, 32);

    __shared__ float wsum[4];
    const int wave = threadIdx.x >> 6;
    const int lane = threadIdx.x & 63;
    if (lane == 0) wsum[wave] = s;
    __syncthreads();
    if (threadIdx.x == 0)
        out[0] = (wsum[0] + wsum[1] + wsum[2] + wsum[3]) * inv_total;
}

extern "C" void kernel_launch(void* const* d_in, const int* in_sizes, int n_in,
                              void* d_out, int out_size, void* d_ws, size_t ws_size,
                              hipStream_t stream) {
    const float* preds   = (const float*)d_in[0];
    const int*   targets = (const int*)d_in[1];
    float*       out     = (float*)d_out;
    float*       partial = (float*)d_ws;

    const int n_tiles  = in_sizes[0] / NUM_CLASSES;   // 32768
    const int n_blocks = n_tiles / 32;                // 1024 slabs
    const float inv_total = 1.0f / (float)(n_tiles * NUM_CLASSES);

    seg_loss_partial<<<n_blocks, 512, 0, stream>>>(preds, targets, partial);
    seg_loss_reduce<<<1, 256, 0, stream>>>(partial, out, inv_total, n_blocks);
}